// Round 1
// baseline (112.914 us; speedup 1.0000x reference)
//
#include <hip/hip_runtime.h>
#include <stdint.h>

// FibonacciKAN: y[b,o] = sum_i sum_d F_d(tanh(x[b,i])) * C[i,o,d]
// F0..F5 = {0, 1, t, t^2+1, t^3+2t, t^4+3t^2+1}
// => y = bias[o] + sum_i ( t*W0 + t^2*W1 + t^3*W2 + t^4*W3 )[i,o]
//    W0=C2+2C4, W1=C3+3C5, W2=C4, W3=C5, bias=sum_i(C1+C3+C5)
// GEMM: M=32768, N=256, K=1024 (k = i*4 + p, p -> power p+1), bf16 MFMA 16x16x32.
// Workspace: bias (1 KB) + Bp repacked frag-ordered bf16 B matrix (512 KB).

typedef short bf16x8 __attribute__((ext_vector_type(8)));
typedef float f32x4 __attribute__((ext_vector_type(4)));
typedef unsigned int uint4v __attribute__((ext_vector_type(4)));

__device__ __forceinline__ unsigned int pack_bf16_trunc(float a, float b) {
  // low16 = bf16(a) (truncated), high16 = bf16(b): one v_perm_b32
  return __builtin_amdgcn_perm(__float_as_uint(b), __float_as_uint(a), 0x07060302u);
}
__device__ __forceinline__ unsigned int round_bf16_bits(float a) {
  unsigned int u = __float_as_uint(a);
  return u + 0x7fffu + ((u >> 16) & 1u);  // RNE bias; result bf16 in high 16
}
__device__ __forceinline__ unsigned int pack_bf16_rne(float a, float b) {
  return __builtin_amdgcn_perm(round_bf16_bits(b), round_bf16_bits(a), 0x07060302u);
}
__device__ __forceinline__ float fast_tanh(float x) {
  // tanh(x) = 1 - 2/(exp(2x)+1); exp2f -> v_exp_f32, rcp -> v_rcp_f32.
  // |err| ~1e-6 abs, far below bf16 quantization (2^-9 rel).
  float e = exp2f(x * 2.8853900817779268f);  // 2*log2(e)
  return 1.0f - 2.0f * __builtin_amdgcn_rcpf(e + 1.0f);
}

// ---------------- prep: repack coeffs into MFMA-B-frag order + bias ----------
// Bp element layout (bf16): Bp[((ks*16 + ntg)*64 + lane)*8 + j]
//   = W[k = ks*32 + (lane>>4)*8 + j][n = ntg*16 + (lane&15)]
// so a lane's B-frag for (ks, ntg) is one contiguous 16 B global_load_dwordx4.
__global__ void prep_kernel(const float* __restrict__ C, short* __restrict__ Bp,
                            float* __restrict__ bias) {
  int i = blockIdx.x;    // 0..255 input dim
  int n = threadIdx.x;   // 0..255 output dim
  const float* c = C + (i * 256 + n) * 6;
  float c1 = c[1], c2 = c[2], c3 = c[3], c4_ = c[4], c5 = c[5];
  float w0 = c2 + 2.0f * c4_;  // coeff of t^1   (k = i*4 + 0)
  float w1 = c3 + 3.0f * c5;   // coeff of t^2
  unsigned int r0 = pack_bf16_rne(w0, w1);
  unsigned int r1 = pack_bf16_rne(c4_, c5);  // t^3, t^4
  // k = i*4 + p -> ks = i>>3, lane_hi = (i>>1)&3, j = (i&1)*4 + p
  int ks = i >> 3;
  int lane = (((i >> 1) & 3) << 4) | (n & 15);
  int ntg = n >> 4;
  int off = (((ks * 16 + ntg) * 64 + lane) << 3) + ((i & 1) << 2);
  *(uint2*)(Bp + off) = make_uint2(r0, r1);
  atomicAdd(bias + n, c1 + c3 + c5);
}

// ---------------- fused tanh + powers + GEMM ----------------
// Block tile 128x128, 4 waves in 2x2 of 64x64 wave tiles, 4x4 16x16x32 MFMA.
// t = tanh(x) staged once per block in LDS (bf16, row stride 260 => 8B-aligned
// rows, 2-way-max bank pattern on the b32 pair reads, which is free).
// K-loop has NO barriers: A-frags built in regs from LDS t, B-frags straight
// from L2-resident Bp.
__global__ __launch_bounds__(256, 2) void fibkan_gemm(
    const float* __restrict__ x, const short* __restrict__ Bp,
    const float* __restrict__ bias, float* __restrict__ y) {
  __shared__ unsigned short tl[128 * 260];  // 66560 B
  const int tid = threadIdx.x;
  const int lane = tid & 63;
  const int wv = tid >> 6;
  const int wm = wv >> 1, wn = wv & 1;
  const int mb = blockIdx.x >> 1, nb = blockIdx.x & 1;

  // ---- stage t = tanh(x) tile: 128 rows x 256 cols ----
  {
    const float4* xp = (const float4*)(x + mb * 128 * 256);
#pragma unroll 4
    for (int it = 0; it < 32; ++it) {
      int j = tid + it * 256;        // float4 index, 0..8191
      int row = j >> 6, c4i = j & 63;
      float4 v = xp[j];
      float t0 = fast_tanh(v.x), t1 = fast_tanh(v.y);
      float t2 = fast_tanh(v.z), t3 = fast_tanh(v.w);
      uint2 pk = make_uint2(pack_bf16_rne(t0, t1), pack_bf16_rne(t2, t3));
      *(uint2*)&tl[row * 260 + c4i * 4] = pk;  // ds_write_b64
    }
  }
  __syncthreads();

  f32x4 acc[4][4] = {};

  const int lhi = lane >> 4, llo = lane & 15;
  // t pair pointer: row = wm*64 + mt*16 + llo, col = ks*8 + lhi*2
  const unsigned short* tp0 = &tl[(wm * 64 + llo) * 260 + lhi * 2];
  // B-frag pointer: frag idx = (ks*16 + ntg)*64 + lane, ntg0 = nb*8 + wn*4
  const bf16x8* bp = (const bf16x8*)Bp + ((nb * 8 + wn * 4) * 64 + lane);

  unsigned int tcur[4], tnxt[4];
  bf16x8 bcur[4], bnxt[4];
#pragma unroll
  for (int mt = 0; mt < 4; ++mt)
    tcur[mt] = *(const unsigned int*)(tp0 + mt * 16 * 260);
#pragma unroll
  for (int nt = 0; nt < 4; ++nt) bcur[nt] = bp[nt * 64];

  for (int ks = 0; ks < 32; ++ks) {
    int ksn = (ks + 1) & 31;  // wraps to 0 on last iter (harmless reload)
    // prefetch next K-step
#pragma unroll
    for (int nt = 0; nt < 4; ++nt) bnxt[nt] = bp[ksn * 1024 + nt * 64];
#pragma unroll
    for (int mt = 0; mt < 4; ++mt)
      tnxt[mt] = *(const unsigned int*)(tp0 + mt * 16 * 260 + ksn * 8);
    // build A-frags: per lane 8 bf16 = (t,t^2,t^3,t^4) for i0 and i0+1
    bf16x8 af[4];
#pragma unroll
    for (int mt = 0; mt < 4; ++mt) {
      unsigned int tp2 = tcur[mt];
      float ta = __uint_as_float(tp2 << 16);
      float tb = __uint_as_float(tp2 & 0xffff0000u);
      float ta2 = ta * ta, tb2 = tb * tb;
      float ta3 = ta2 * ta, tb3 = tb2 * tb;
      float ta4 = ta2 * ta2, tb4 = tb2 * tb2;
      uint4v u = {pack_bf16_trunc(ta, ta2), pack_bf16_trunc(ta3, ta4),
                  pack_bf16_trunc(tb, tb2), pack_bf16_trunc(tb3, tb4)};
      af[mt] = __builtin_bit_cast(bf16x8, u);
    }
#pragma unroll
    for (int mt = 0; mt < 4; ++mt)
#pragma unroll
      for (int nt = 0; nt < 4; ++nt)
        acc[mt][nt] = __builtin_amdgcn_mfma_f32_16x16x32_bf16(
            af[mt], bcur[nt], acc[mt][nt], 0, 0, 0);
#pragma unroll
    for (int nt = 0; nt < 4; ++nt) bcur[nt] = bnxt[nt];
#pragma unroll
    for (int mt = 0; mt < 4; ++mt) tcur[mt] = tnxt[mt];
  }

  // epilogue: C/D layout col = lane&15, row = (lane>>4)*4 + reg  [m89]
  const int col0 = nb * 128 + wn * 64 + llo;
  const int row0 = mb * 128 + wm * 64 + lhi * 4;
#pragma unroll
  for (int nt = 0; nt < 4; ++nt) {
    float bv = bias[col0 + nt * 16];
#pragma unroll
    for (int mt = 0; mt < 4; ++mt) {
#pragma unroll
      for (int r = 0; r < 4; ++r) {
        y[(row0 + mt * 16 + r) * 256 + col0 + nt * 16] = acc[mt][nt][r] + bv;
      }
    }
  }
}

extern "C" void kernel_launch(void* const* d_in, const int* in_sizes, int n_in,
                              void* d_out, int out_size, void* d_ws, size_t ws_size,
                              hipStream_t stream) {
  const float* x = (const float*)d_in[0];        // [32768, 256] f32
  const float* C = (const float*)d_in[1];        // [256, 256, 6] f32
  float* y = (float*)d_out;                      // [32768, 256] f32
  float* bias = (float*)d_ws;                    // 256 f32
  short* Bp = (short*)((char*)d_ws + 1024);      // 1024x256 bf16, frag-ordered
  // needs ws_size >= 1024 + 512 KB
  hipMemsetAsync(bias, 0, 256 * sizeof(float), stream);
  prep_kernel<<<256, 256, 0, stream>>>(C, Bp, bias);
  fibkan_gemm<<<512, 256, 0, stream>>>(x, Bp, bias, y);
}

// Round 2
// 107.787 us; speedup vs baseline: 1.0476x; 1.0476x over previous
//
#include <hip/hip_runtime.h>
#include <stdint.h>

// FibonacciKAN: y[b,o] = sum_i sum_d F_d(tanh(x[b,i])) * C[i,o,d]
// F0..F5 = {0, 1, t, t^2+1, t^3+2t, t^4+3t^2+1}
// => y = bias[o] + sum_i ( t*W0 + t^2*W1 + t^3*W2 + t^4*W3 )[i,o]
//    W0=C2+2C4, W1=C3+3C5, W2=C4, W3=C5, bias=sum_i(C1+C3+C5)
// GEMM: M=32768, N=256, K=1024 (k = i*4 + p, p -> power p+1), bf16 MFMA 16x16x32.
// Workspace: bias (1 KB) + Bp repacked frag-ordered bf16 B matrix (512 KB).
//
// R2 change: prep no longer does 65536 atomicAdds onto 4 cache lines (TCC
// serialization ~25-30 us). bias computed by wave-reduction blocks fused into
// the same launch; hipMemsetAsync dropped. GEMM unchanged from R1 (passed,
// absmax 9.8e-4).

typedef short bf16x8 __attribute__((ext_vector_type(8)));
typedef float f32x4 __attribute__((ext_vector_type(4)));
typedef unsigned int uint4v __attribute__((ext_vector_type(4)));

__device__ __forceinline__ unsigned int pack_bf16_trunc(float a, float b) {
  // low16 = bf16(a) (truncated), high16 = bf16(b): one v_perm_b32
  return __builtin_amdgcn_perm(__float_as_uint(b), __float_as_uint(a), 0x07060302u);
}
__device__ __forceinline__ unsigned int round_bf16_bits(float a) {
  unsigned int u = __float_as_uint(a);
  return u + 0x7fffu + ((u >> 16) & 1u);  // RNE bias; result bf16 in high 16
}
__device__ __forceinline__ unsigned int pack_bf16_rne(float a, float b) {
  return __builtin_amdgcn_perm(round_bf16_bits(b), round_bf16_bits(a), 0x07060302u);
}
__device__ __forceinline__ float fast_tanh(float x) {
  // tanh(x) = 1 - 2/(exp(2x)+1); exp2f -> v_exp_f32, rcp -> v_rcp_f32.
  float e = exp2f(x * 2.8853900817779268f);  // 2*log2(e)
  return 1.0f - 2.0f * __builtin_amdgcn_rcpf(e + 1.0f);
}

// ---------------- prep: repack coeffs into MFMA-B-frag order + bias ----------
// Blocks 0..255: Bp repack (block = i, thread = n) — identical to R1.
// Blocks 256..319: bias. Each wave owns one n; lane t sums i in {t,t+64,...},
// butterfly-reduce, lane 0 stores. No atomics anywhere.
__global__ void prep_kernel(const float* __restrict__ C, short* __restrict__ Bp,
                            float* __restrict__ bias) {
  int b = blockIdx.x;
  if (b < 256) {
    int i = b;             // 0..255 input dim
    int n = threadIdx.x;   // 0..255 output dim
    const float* c = C + (i * 256 + n) * 6;
    float c2 = c[2], c3 = c[3], c4_ = c[4], c5 = c[5];
    float w0 = c2 + 2.0f * c4_;  // coeff of t^1   (k = i*4 + 0)
    float w1 = c3 + 3.0f * c5;   // coeff of t^2
    unsigned int r0 = pack_bf16_rne(w0, w1);
    unsigned int r1 = pack_bf16_rne(c4_, c5);  // t^3, t^4
    // k = i*4 + p -> ks = i>>3, lane_hi = (i>>1)&3, j = (i&1)*4 + p
    int ks = i >> 3;
    int lane = (((i >> 1) & 3) << 4) | (n & 15);
    int ntg = n >> 4;
    int off = (((ks * 16 + ntg) * 64 + lane) << 3) + ((i & 1) << 2);
    *(uint2*)(Bp + off) = make_uint2(r0, r1);
  } else {
    int w = threadIdx.x >> 6;     // wave 0..3
    int t = threadIdx.x & 63;     // lane
    int n = (b - 256) * 4 + w;    // 0..255
    float s = 0.0f;
#pragma unroll
    for (int r = 0; r < 4; ++r) {
      int i = t + r * 64;
      const float* c = C + (i * 256 + n) * 6;
      s += c[1] + c[3] + c[5];
    }
#pragma unroll
    for (int off = 32; off > 0; off >>= 1) s += __shfl_down(s, off);
    if (t == 0) bias[n] = s;
  }
}

// ---------------- fused tanh + powers + GEMM (unchanged from R1) ----------
__global__ __launch_bounds__(256, 2) void fibkan_gemm(
    const float* __restrict__ x, const short* __restrict__ Bp,
    const float* __restrict__ bias, float* __restrict__ y) {
  __shared__ unsigned short tl[128 * 260];  // 66560 B
  const int tid = threadIdx.x;
  const int lane = tid & 63;
  const int wv = tid >> 6;
  const int wm = wv >> 1, wn = wv & 1;
  const int mb = blockIdx.x >> 1, nb = blockIdx.x & 1;

  // ---- stage t = tanh(x) tile: 128 rows x 256 cols ----
  {
    const float4* xp = (const float4*)(x + mb * 128 * 256);
#pragma unroll 4
    for (int it = 0; it < 32; ++it) {
      int j = tid + it * 256;        // float4 index, 0..8191
      int row = j >> 6, c4i = j & 63;
      float4 v = xp[j];
      float t0 = fast_tanh(v.x), t1 = fast_tanh(v.y);
      float t2 = fast_tanh(v.z), t3 = fast_tanh(v.w);
      uint2 pk = make_uint2(pack_bf16_rne(t0, t1), pack_bf16_rne(t2, t3));
      *(uint2*)&tl[row * 260 + c4i * 4] = pk;  // ds_write_b64
    }
  }
  __syncthreads();

  f32x4 acc[4][4] = {};

  const int lhi = lane >> 4, llo = lane & 15;
  // t pair pointer: row = wm*64 + mt*16 + llo, col = ks*8 + lhi*2
  const unsigned short* tp0 = &tl[(wm * 64 + llo) * 260 + lhi * 2];
  // B-frag pointer: frag idx = (ks*16 + ntg)*64 + lane, ntg0 = nb*8 + wn*4
  const bf16x8* bp = (const bf16x8*)Bp + ((nb * 8 + wn * 4) * 64 + lane);

  unsigned int tcur[4], tnxt[4];
  bf16x8 bcur[4], bnxt[4];
#pragma unroll
  for (int mt = 0; mt < 4; ++mt)
    tcur[mt] = *(const unsigned int*)(tp0 + mt * 16 * 260);
#pragma unroll
  for (int nt = 0; nt < 4; ++nt) bcur[nt] = bp[nt * 64];

  for (int ks = 0; ks < 32; ++ks) {
    int ksn = (ks + 1) & 31;  // wraps to 0 on last iter (harmless reload)
    // prefetch next K-step
#pragma unroll
    for (int nt = 0; nt < 4; ++nt) bnxt[nt] = bp[ksn * 1024 + nt * 64];
#pragma unroll
    for (int mt = 0; mt < 4; ++mt)
      tnxt[mt] = *(const unsigned int*)(tp0 + mt * 16 * 260 + ksn * 8);
    // build A-frags: per lane 8 bf16 = (t,t^2,t^3,t^4) for i0 and i0+1
    bf16x8 af[4];
#pragma unroll
    for (int mt = 0; mt < 4; ++mt) {
      unsigned int tp2 = tcur[mt];
      float ta = __uint_as_float(tp2 << 16);
      float tb = __uint_as_float(tp2 & 0xffff0000u);
      float ta2 = ta * ta, tb2 = tb * tb;
      float ta3 = ta2 * ta, tb3 = tb2 * tb;
      float ta4 = ta2 * ta2, tb4 = tb2 * tb2;
      uint4v u = {pack_bf16_trunc(ta, ta2), pack_bf16_trunc(ta3, ta4),
                  pack_bf16_trunc(tb, tb2), pack_bf16_trunc(tb3, tb4)};
      af[mt] = __builtin_bit_cast(bf16x8, u);
    }
#pragma unroll
    for (int mt = 0; mt < 4; ++mt)
#pragma unroll
      for (int nt = 0; nt < 4; ++nt)
        acc[mt][nt] = __builtin_amdgcn_mfma_f32_16x16x32_bf16(
            af[mt], bcur[nt], acc[mt][nt], 0, 0, 0);
#pragma unroll
    for (int nt = 0; nt < 4; ++nt) bcur[nt] = bnxt[nt];
#pragma unroll
    for (int mt = 0; mt < 4; ++mt) tcur[mt] = tnxt[mt];
  }

  // epilogue: C/D layout col = lane&15, row = (lane>>4)*4 + reg  [m89]
  const int col0 = nb * 128 + wn * 64 + llo;
  const int row0 = mb * 128 + wm * 64 + lhi * 4;
#pragma unroll
  for (int nt = 0; nt < 4; ++nt) {
    float bv = bias[col0 + nt * 16];
#pragma unroll
    for (int mt = 0; mt < 4; ++mt) {
#pragma unroll
      for (int r = 0; r < 4; ++r) {
        y[(row0 + mt * 16 + r) * 256 + col0 + nt * 16] = acc[mt][nt][r] + bv;
      }
    }
  }
}

extern "C" void kernel_launch(void* const* d_in, const int* in_sizes, int n_in,
                              void* d_out, int out_size, void* d_ws, size_t ws_size,
                              hipStream_t stream) {
  const float* x = (const float*)d_in[0];        // [32768, 256] f32
  const float* C = (const float*)d_in[1];        // [256, 256, 6] f32
  float* y = (float*)d_out;                      // [32768, 256] f32
  float* bias = (float*)d_ws;                    // 256 f32
  short* Bp = (short*)((char*)d_ws + 1024);      // 1024x256 bf16, frag-ordered
  // needs ws_size >= 1024 + 512 KB
  prep_kernel<<<320, 256, 0, stream>>>(C, Bp, bias);
  fibkan_gemm<<<512, 256, 0, stream>>>(x, Bp, bias, y);
}